// Round 1
// 742.787 us; speedup vs baseline: 1.0371x; 1.0371x over previous
//
#include <hip/hip_runtime.h>

#define VOCAB 400000
#define DIM   300
#define HID   32
#define NOUT  2
#define BATCH 16384
#define SEQ   50

// K1: one wave (64 lanes) per batch row.
//
// Phase 1 (gather): lane l owns float4 index l (dims 4l..4l+3); lanes 0..10
// also own float4 64+l (dims 256..299). 50 embedding rows accumulated in
// registers; rows are 1200 B (16B-aligned). unroll 5 keeps ~10 gathers in
// flight per wave.
//
// Phase 2 (matmul): pooled vector staged to per-wave LDS. Each lane computes
// one hidden unit k = lane&31 over half the dims (halves split 152/148),
// LDS reads are 2-address broadcasts (conflict-free), V_w rows are L1/L2-hot.
// One shfl_xor(32) merges halves; 10 shfl reduce the 2 logits.
// This replaces the old hp[32]-register butterfly (192 shfl, +32 VGPRs held
// for the whole kernel) -> VGPR <= 64 target, 8 blocks/CU for gather hiding.
__global__ __launch_bounds__(256, 8) void dan_main(
    const int*   __restrict__ tokens,
    const float* __restrict__ emb,
    const float* __restrict__ Vw,
    const float* __restrict__ Vb,
    const float* __restrict__ Ww,
    const float* __restrict__ Wb,
    float*       __restrict__ logits)
{
    const int wave = threadIdx.x >> 6;
    const int lane = threadIdx.x & 63;
    const int row  = blockIdx.x * 4 + wave;   // grid is exact: row < BATCH

    const int* toks = tokens + row * SEQ;
    const bool has1 = (lane < (DIM / 4 - 64));  // lanes 0..10

    float4 acc0 = make_float4(0.f, 0.f, 0.f, 0.f);
    float4 acc1 = make_float4(0.f, 0.f, 0.f, 0.f);

    #pragma unroll 5
    for (int s = 0; s < SEQ; ++s) {
        const int t = toks[s];  // wave-uniform address
        const float4* e = (const float4*)(emb + (size_t)t * DIM);
        float4 v0 = e[lane];
        acc0.x += v0.x; acc0.y += v0.y; acc0.z += v0.z; acc0.w += v0.w;
        if (has1) {
            float4 v1 = e[64 + lane];
            acc1.x += v1.x; acc1.y += v1.y; acc1.z += v1.z; acc1.w += v1.w;
        }
    }
    const float inv = 1.0f / (float)SEQ;
    acc0.x *= inv; acc0.y *= inv; acc0.z *= inv; acc0.w *= inv;

    // Stage pooled[300] to LDS (per-wave slice; 1216 B each, 16B-aligned).
    __shared__ float pool[4][304];
    *(float4*)&pool[wave][4 * lane] = acc0;
    if (has1) {
        acc1.x *= inv; acc1.y *= inv; acc1.z *= inv; acc1.w *= inv;
        *(float4*)&pool[wave][256 + 4 * lane] = acc1;
    }
    __syncthreads();

    // k = lane&31 hidden unit; half 0 -> dims 0..151 (38 f4), half 1 -> 152..299 (37 f4)
    const int k    = lane & 31;
    const int half = lane >> 5;
    const int base = half ? 152 : 0;
    const float* __restrict__ vrow = Vw + k * DIM + base;   // 16B-aligned (1200,608 % 16 == 0)
    const float* pw = &pool[wave][base];

    float p = 0.f;
    #pragma unroll
    for (int i = 0; i < 37; ++i) {
        float4 a = *(const float4*)(pw + 4 * i);        // LDS broadcast read
        float4 w = *(const float4*)(vrow + 4 * i);      // L1/L2-hot (38.4 KB table)
        p += a.x * w.x + a.y * w.y + a.z * w.z + a.w * w.w;
    }
    if (!half) {  // extra float4: dims 148..151
        float4 a = *(const float4*)(pw + 148);
        float4 w = *(const float4*)(vrow + 148);
        p += a.x * w.x + a.y * w.y + a.z * w.z + a.w * w.w;
    }
    p += __shfl_xor(p, 32, 64);   // both halves now hold full dot for k

    float hv = fmaxf(p + Vb[k], 0.f);      // relu(pooled . V_w[k] + V_b[k])
    float g0 = hv * Ww[k];                 // W_w[0][k]
    float g1 = hv * Ww[HID + k];           // W_w[1][k]
    #pragma unroll
    for (int m = 1; m < 32; m <<= 1) {     // sum over k within each 32-half
        g0 += __shfl_xor(g0, m, 64);
        g1 += __shfl_xor(g1, m, 64);
    }
    if (lane == 0) {
        logits[row * 2 + 0] = g0 + Wb[0];
        logits[row * 2 + 1] = g1 + Wb[1];
    }
}

// K2 (fused reduce + final): single block computes per-column (axis=0) max and
// log-sum-exp over the 16384 rows, then writes out[b][j] = logits[b][j] - c[j].
// Total traffic ~384 KB -> a few us; fusing removes one kernel launch.
__global__ __launch_bounds__(1024) void dan_reduce_final(
    const float* __restrict__ logits, float* __restrict__ out)
{
    __shared__ float r0[1024];
    __shared__ float r1[1024];
    const int tid = threadIdx.x;

    float m0 = -INFINITY, m1 = -INFINITY;
    for (int b = tid; b < BATCH; b += 1024) {
        m0 = fmaxf(m0, logits[b * 2 + 0]);
        m1 = fmaxf(m1, logits[b * 2 + 1]);
    }
    r0[tid] = m0; r1[tid] = m1;
    __syncthreads();
    for (int s = 512; s > 0; s >>= 1) {
        if (tid < s) {
            r0[tid] = fmaxf(r0[tid], r0[tid + s]);
            r1[tid] = fmaxf(r1[tid], r1[tid + s]);
        }
        __syncthreads();
    }
    m0 = r0[0]; m1 = r1[0];
    __syncthreads();

    float s0 = 0.f, s1 = 0.f;
    for (int b = tid; b < BATCH; b += 1024) {
        s0 += __expf(logits[b * 2 + 0] - m0);
        s1 += __expf(logits[b * 2 + 1] - m1);
    }
    r0[tid] = s0; r1[tid] = s1;
    __syncthreads();
    for (int s = 512; s > 0; s >>= 1) {
        if (tid < s) {
            r0[tid] += r0[tid + s];
            r1[tid] += r1[tid + s];
        }
        __syncthreads();
    }
    // after the final tree step + barrier, r0[0]/r1[0] visible to all threads
    const float c0 = m0 + __logf(r0[0]);
    const float c1 = m1 + __logf(r1[0]);
    for (int i = tid; i < BATCH * NOUT; i += 1024) {
        out[i] = logits[i] - ((i & 1) ? c1 : c0);
    }
}

extern "C" void kernel_launch(void* const* d_in, const int* in_sizes, int n_in,
                              void* d_out, int out_size, void* d_ws, size_t ws_size,
                              hipStream_t stream) {
    const int*   tokens = (const int*)  d_in[0];
    const float* emb    = (const float*)d_in[1];
    const float* Vw     = (const float*)d_in[2];
    const float* Vb     = (const float*)d_in[3];
    const float* Ww     = (const float*)d_in[4];
    const float* Wb     = (const float*)d_in[5];
    float* out    = (float*)d_out;
    float* logits = (float*)d_ws;   // BATCH*NOUT floats = 128 KB

    dan_main        <<<BATCH / 4, 256, 0, stream>>>(tokens, emb, Vw, Vb, Ww, Wb, logits);
    dan_reduce_final<<<1, 1024, 0, stream>>>(logits, out);
}